// Round 1
// 1511.856 us; speedup vs baseline: 1.2052x; 1.2052x over previous
//
#include <hip/hip_runtime.h>

#define F0 256
#define HD 128
#define NP 100352   // padded rows (784*128)

typedef unsigned short u16;
typedef __attribute__((ext_vector_type(8))) short short8;
typedef __attribute__((ext_vector_type(4))) float f32x4;

__device__ inline float bf2f(u16 u) {
    union { unsigned int i; float f; } v; v.i = ((unsigned int)u) << 16; return v.f;
}
__device__ inline u16 f2bf(float f) {
    union { float f; unsigned int i; } v; v.f = f;
    unsigned int r = v.i + 0x7FFF + ((v.i >> 16) & 1);
    return (u16)(r >> 16);
}

#define GLOAD16(gp, lp) __builtin_amdgcn_global_load_lds( \
    (const __attribute__((address_space(1))) void*)(gp), \
    (__attribute__((address_space(3))) void*)(lp), 16, 0, 0)

// ---------------------------------------------------------------------------
// CSR build: hist -> scan -> single scatter of packed (col, val)
// ---------------------------------------------------------------------------
__global__ void k_hist(const int* __restrict__ row, int* __restrict__ counts, int E) {
    int e = blockIdx.x * blockDim.x + threadIdx.x;
    if (e < E) atomicAdd(&counts[row[e]], 1);
}

__global__ void k_scan_blk(const int* __restrict__ counts, int* __restrict__ scan_out,
                           int* __restrict__ partials, int n) {
    __shared__ int wsum[16];
    int t = threadIdx.x;
    int i = blockIdx.x * 1024 + t;
    int v = (i < n) ? counts[i] : 0;
    int lane = t & 63, w = t >> 6;
    #pragma unroll
    for (int off = 1; off < 64; off <<= 1) { int u = __shfl_up(v, off); if (lane >= off) v += u; }
    if (lane == 63) wsum[w] = v;
    __syncthreads();
    if (t < 16) {
        int s = wsum[t];
        #pragma unroll
        for (int off = 1; off < 16; off <<= 1) { int u = __shfl_up(s, off); if (t >= off) s += u; }
        wsum[t] = s;
    }
    __syncthreads();
    int add = (w > 0) ? wsum[w - 1] : 0;
    if (i < n) scan_out[i] = v + add;
    if (t == 1023) partials[blockIdx.x] = wsum[15];
}

__global__ void k_scan_part(int* partials, int nb) {
    __shared__ int ws2[2];
    int t = threadIdx.x;
    int v = (t < nb) ? partials[t] : 0;
    int lane = t & 63, w = t >> 6;
    #pragma unroll
    for (int off = 1; off < 64; off <<= 1) { int u = __shfl_up(v, off); if (lane >= off) v += u; }
    if (lane == 63) ws2[w] = v;
    __syncthreads();
    if (w == 1) v += ws2[0];
    if (t < nb) partials[t] = v;
}

__global__ void k_scan_add(int* __restrict__ row_ptr, const int* __restrict__ partials, int n) {
    int b = blockIdx.x;
    int i = b * 1024 + threadIdx.x;
    if (b == 0 && threadIdx.x == 0) row_ptr[0] = 0;
    int add = (b > 0) ? partials[b - 1] : 0;
    if (i < n) row_ptr[1 + i] += add;
}

// one pass: coalesced reads of erow/ecol/avals, one random 8B write per edge
__global__ void k_scatter_cv(const int* __restrict__ row, const int* __restrict__ ecol,
                             const float* __restrict__ avals, const int* __restrict__ row_ptr,
                             int* __restrict__ cursor, int2* __restrict__ cv, int E) {
    int e = blockIdx.x * blockDim.x + threadIdx.x;
    if (e >= E) return;
    int r = row[e];
    int pos = row_ptr[r] + atomicAdd(&cursor[r], 1);
    cv[pos] = make_int2(ecol[e], __float_as_int(avals[e]));
}

// ---------------------------------------------------------------------------
// casts
// ---------------------------------------------------------------------------
__global__ void k_cast_x(const float* __restrict__ x, u16* __restrict__ xb, int total4) {
    int i = blockIdx.x * blockDim.x + threadIdx.x;
    if (i >= total4) return;
    float4 v = ((const float4*)x)[i];
    ((ushort4*)xb)[i] = make_ushort4(f2bf(v.x), f2bf(v.y), f2bf(v.z), f2bf(v.w));
}

__global__ void k_prep_w(const float* __restrict__ W_gc1, const float* __restrict__ W_gc2,
                         const float* __restrict__ Wg1, const float* __restrict__ Wxp,
                         const float* __restrict__ Wq, const float* __restrict__ Wk,
                         const float* __restrict__ Wv,
                         u16* Wgc1t, u16* Wgc2t, u16* Wdt, u16* W1t, u16* W2t,
                         u16* Wxpt, u16* Wqt, u16* Wkt, u16* Wvt) {
    int z = blockIdx.z;
    int idx = blockIdx.x * 256 + threadIdx.x;
    if (z == 0) { if (idx < 65536) { int n = idx >> 8, k = idx & 255; Wgc1t[idx] = f2bf(W_gc1[k * 256 + n]); } }
    else if (z == 1) { if (idx < 32768) { int n = idx >> 8, k = idx & 255; Wgc2t[idx] = f2bf(W_gc2[k * 128 + n]); } }
    else if (z == 2) { if (idx < 32768) { int n = idx >> 8, k = idx & 255; Wdt[idx] = f2bf(Wg1[k * 128 + n] - Wg1[(k + 256) * 128 + n]); } }
    else if (z == 3) { if (idx < 32768) { int n = idx >> 8, k = idx & 255; W1t[idx] = f2bf(Wg1[(k + 256) * 128 + n]); } }
    else if (z == 4) { if (idx < 32768) { int n = idx >> 8, k = idx & 255; W2t[idx] = f2bf(Wg1[(k + 512) * 128 + n]); } }
    else if (z == 5) { if (idx < 32768) { int n = idx >> 8, k = idx & 255; Wxpt[idx] = f2bf(Wxp[k * 128 + n]); } }
    else if (z == 6) { if (idx < 16384) { int n = idx >> 7, k = idx & 127; Wqt[idx] = f2bf(Wq[k * 128 + n]); } }
    else if (z == 7) { if (idx < 16384) { int n = idx >> 7, k = idx & 127; Wkt[idx] = f2bf(Wk[k * 128 + n]); } }
    else if (z == 8) { if (idx < 16384) { int n = idx >> 7, k = idx & 127; Wvt[idx] = f2bf(Wv[k * 128 + n]); } }
}

// ---------------------------------------------------------------------------
// SpMM over x with fused mean/std finalize: bf16 AX + bf16 XSTD + deg directly
// (every lane accumulates full deg, so the finalize is register-local)
// ---------------------------------------------------------------------------
__global__ void k_spmm_x2(const u16* __restrict__ Xb, const int* __restrict__ row_ptr,
                          const int2* __restrict__ cv,
                          u16* __restrict__ AXb, u16* __restrict__ XSTDb,
                          float* __restrict__ deg, int N) {
    int wid = blockIdx.x * 4 + (threadIdx.x >> 6);
    if (wid >= N) return;
    int lane = threadIdx.x & 63;
    float a0 = 0, a1 = 0, a2 = 0, a3 = 0;
    float q0 = 0, q1 = 0, q2 = 0, q3 = 0, d = 0;
    int s = row_ptr[wid], e = row_ptr[wid + 1];
    int j = s;
    for (; j + 3 < e; j += 4) {
        int2 cc[4]; ushort4 xb[4];
        #pragma unroll
        for (int t = 0; t < 4; ++t) cc[t] = cv[j + t];
        #pragma unroll
        for (int t = 0; t < 4; ++t) xb[t] = *(const ushort4*)(Xb + (size_t)cc[t].x * F0 + lane * 4);
        #pragma unroll
        for (int t = 0; t < 4; ++t) {
            float x0 = bf2f(xb[t].x), x1 = bf2f(xb[t].y), x2 = bf2f(xb[t].z), x3 = bf2f(xb[t].w);
            float vv = __int_as_float(cc[t].y);
            a0 += vv * x0; a1 += vv * x1; a2 += vv * x2; a3 += vv * x3;
            q0 += vv * x0 * x0; q1 += vv * x1 * x1; q2 += vv * x2 * x2; q3 += vv * x3 * x3;
            d += vv;
        }
    }
    for (; j < e; ++j) {
        int2 cc = cv[j];
        float v0 = __int_as_float(cc.y);
        ushort4 xb0 = *(const ushort4*)(Xb + (size_t)cc.x * F0 + lane * 4);
        float x0 = bf2f(xb0.x), x1 = bf2f(xb0.y), x2 = bf2f(xb0.z), x3 = bf2f(xb0.w);
        a0 += v0 * x0; a1 += v0 * x1; a2 += v0 * x2; a3 += v0 * x3;
        q0 += v0 * x0 * x0; q1 += v0 * x1 * x1; q2 += v0 * x2 * x2; q3 += v0 * x3 * x3;
        d += v0;
    }
    float inv = 1.0f / (d + 1e-8f);
    float m0 = a0 * inv, m1 = a1 * inv, m2 = a2 * inv, m3 = a3 * inv;
    float s0 = sqrtf(fmaxf(q0 * inv - m0 * m0, 0.f));
    float s1 = sqrtf(fmaxf(q1 * inv - m1 * m1, 0.f));
    float s2 = sqrtf(fmaxf(q2 * inv - m2 * m2, 0.f));
    float s3 = sqrtf(fmaxf(q3 * inv - m3 * m3, 0.f));
    *(ushort4*)(AXb + (size_t)wid * F0 + lane * 4) = make_ushort4(f2bf(a0), f2bf(a1), f2bf(a2), f2bf(a3));
    *(ushort4*)(XSTDb + (size_t)wid * F0 + lane * 4) = make_ushort4(f2bf(s0), f2bf(s1), f2bf(s2), f2bf(s3));
    if (lane == 0) deg[wid] = d;
}

// bf16 in, bf16 out
__global__ void k_spmm128(const u16* __restrict__ Xb, const int* __restrict__ row_ptr,
                          const int2* __restrict__ cv, u16* __restrict__ OUT, int N) {
    int wid = blockIdx.x * 4 + (threadIdx.x >> 6);
    if (wid >= N) return;
    int lane = threadIdx.x & 63;
    float a0 = 0, a1 = 0;
    int s = row_ptr[wid], e = row_ptr[wid + 1];
    int j = s;
    for (; j + 3 < e; j += 4) {
        int2 cc[4]; ushort2 xb[4];
        #pragma unroll
        for (int t = 0; t < 4; ++t) cc[t] = cv[j + t];
        #pragma unroll
        for (int t = 0; t < 4; ++t) xb[t] = *(const ushort2*)(Xb + (size_t)cc[t].x * HD + lane * 2);
        #pragma unroll
        for (int t = 0; t < 4; ++t) {
            float vv = __int_as_float(cc[t].y);
            a0 += vv * bf2f(xb[t].x); a1 += vv * bf2f(xb[t].y);
        }
    }
    for (; j < e; ++j) {
        int2 cc = cv[j];
        float v0 = __int_as_float(cc.y);
        ushort2 x0 = *(const ushort2*)(Xb + (size_t)cc.x * HD + lane * 2);
        a0 += v0 * bf2f(x0.x); a1 += v0 * bf2f(x0.y);
    }
    *(ushort2*)(OUT + (size_t)wid * HD + lane * 2) = make_ushort2(f2bf(a0), f2bf(a1));
}

// ---------------------------------------------------------------------------
// bf16 MFMA GEMM core: C[128,128] tile = A[M,K] @ Bt[N,K]^T, BK=32
// ---------------------------------------------------------------------------
__device__ inline void mm_core(const u16* __restrict__ A, const u16* __restrict__ Bt,
                               int K, int ldA, int ldB, int m0, int n0,
                               u16* As, u16* Bs, f32x4 acc[4][4]) {
    int t = threadIdx.x, w = t >> 6, l = t & 63;
    int wr = (w >> 1) * 64, wc = (w & 1) * 64;
    int aoff = (wr + (l & 15)) * 32 + (l >> 4) * 8;
    int boff = (wc + (l & 15)) * 32 + (l >> 4) * 8;
    for (int k0 = 0; k0 < K; k0 += 32) {
        __syncthreads();
        #pragma unroll
        for (int s = 0; s < 2; ++s) {
            int i = s * 256 + t;
            int row = i >> 2, ch = i & 3;
            GLOAD16(A + (size_t)(m0 + row) * ldA + k0 + ch * 8, As + i * 8);
            GLOAD16(Bt + (size_t)(n0 + row) * ldB + k0 + ch * 8, Bs + i * 8);
        }
        __syncthreads();
        short8 af[4], bfr[4];
        #pragma unroll
        for (int i = 0; i < 4; ++i) af[i] = *(const short8*)(As + aoff + i * 16 * 32);
        #pragma unroll
        for (int j = 0; j < 4; ++j) bfr[j] = *(const short8*)(Bs + boff + j * 16 * 32);
        #pragma unroll
        for (int i = 0; i < 4; ++i)
            #pragma unroll
            for (int j = 0; j < 4; ++j)
                acc[i][j] = __builtin_amdgcn_mfma_f32_16x16x32_bf16(af[i], bfr[j], acc[i][j], 0, 0, 0);
    }
}

__device__ inline void mm_zero(f32x4 acc[4][4]) {
    #pragma unroll
    for (int i = 0; i < 4; ++i)
        #pragma unroll
        for (int j = 0; j < 4; ++j)
            acc[i][j] = (f32x4){0.f, 0.f, 0.f, 0.f};
}

__global__ __launch_bounds__(256) void k_mm_f32(const u16* __restrict__ A, const u16* __restrict__ Bt,
                                                float* __restrict__ C, const float* __restrict__ bias,
                                                int M, int K, int Nc) {
    __shared__ __align__(16) u16 As[128 * 32];
    __shared__ __align__(16) u16 Bs[128 * 32];
    int m0 = blockIdx.x * 128, n0 = blockIdx.y * 128;
    f32x4 acc[4][4]; mm_zero(acc);
    mm_core(A, Bt, K, K, K, m0, n0, As, Bs, acc);
    int t = threadIdx.x, w = t >> 6, l = t & 63;
    int rbase = m0 + (w >> 1) * 64 + (l >> 4) * 4;
    int cbase = n0 + (w & 1) * 64 + (l & 15);
    #pragma unroll
    for (int j = 0; j < 4; ++j) {
        float bj = bias ? bias[cbase + j * 16] : 0.f;
        #pragma unroll
        for (int i = 0; i < 4; ++i)
            #pragma unroll
            for (int r = 0; r < 4; ++r) {
                int row = rbase + i * 16 + r;
                if (row < M) C[(size_t)row * Nc + cbase + j * 16] = acc[i][j][r] + bj;
            }
    }
}

__global__ __launch_bounds__(256) void k_mm_bf(const u16* __restrict__ A, const u16* __restrict__ Bt,
                                               u16* __restrict__ C, int M, int K, int Nc) {
    __shared__ __align__(16) u16 As[128 * 32];
    __shared__ __align__(16) u16 Bs[128 * 32];
    int m0 = blockIdx.x * 128, n0 = blockIdx.y * 128;
    f32x4 acc[4][4]; mm_zero(acc);
    mm_core(A, Bt, K, K, K, m0, n0, As, Bs, acc);
    int t = threadIdx.x, w = t >> 6, l = t & 63;
    int rbase = m0 + (w >> 1) * 64 + (l >> 4) * 4;
    int cbase = n0 + (w & 1) * 64 + (l & 15);
    #pragma unroll
    for (int j = 0; j < 4; ++j)
        #pragma unroll
        for (int i = 0; i < 4; ++i)
            #pragma unroll
            for (int r = 0; r < 4; ++r) {
                int row = rbase + i * 16 + r;
                if (row < M) C[(size_t)row * Nc + cbase + j * 16] = f2bf(acc[i][j][r]);
            }
}

__global__ __launch_bounds__(256) void k_mm_gate(const u16* A0, const u16* A1, const u16* A2,
                                                 const u16* B0, const u16* B1, const u16* B2,
                                                 float* __restrict__ C, const float* __restrict__ bg1,
                                                 const float* __restrict__ wlast,
                                                 const float* __restrict__ deg, int M) {
    __shared__ __align__(16) u16 As[128 * 32];
    __shared__ __align__(16) u16 Bs[128 * 32];
    int m0 = blockIdx.x * 128;
    f32x4 acc[4][4]; mm_zero(acc);
    mm_core(A0, B0, 256, 256, 256, m0, 0, As, Bs, acc);
    mm_core(A1, B1, 256, 256, 256, m0, 0, As, Bs, acc);
    mm_core(A2, B2, 256, 256, 256, m0, 0, As, Bs, acc);
    int t = threadIdx.x, w = t >> 6, l = t & 63;
    int rbase = m0 + (w >> 1) * 64 + (l >> 4) * 4;
    int cbase = (w & 1) * 64 + (l & 15);
    float wl[4], bg[4];
    #pragma unroll
    for (int j = 0; j < 4; ++j) { wl[j] = wlast[cbase + j * 16]; bg[j] = bg1[cbase + j * 16]; }
    float dg[4][4];
    #pragma unroll
    for (int i = 0; i < 4; ++i)
        #pragma unroll
        for (int r = 0; r < 4; ++r) {
            int row = rbase + i * 16 + r;
            dg[i][r] = (row < M) ? deg[row] : 0.f;
        }
    #pragma unroll
    for (int j = 0; j < 4; ++j)
        #pragma unroll
        for (int i = 0; i < 4; ++i)
            #pragma unroll
            for (int r = 0; r < 4; ++r) {
                int row = rbase + i * 16 + r;
                if (row < M) C[(size_t)row * 128 + cbase + j * 16] = acc[i][j][r] + bg[j] + dg[i][r] * wl[j];
            }
}

// Q -> f32, K/V -> bf16
__global__ __launch_bounds__(256) void k_mm_qkv(const u16* __restrict__ A,
                                                const u16* Wqt, const u16* Wkt, const u16* Wvt,
                                                float* Q, u16* Kb, u16* Vb, int M) {
    __shared__ __align__(16) u16 As[128 * 32];
    __shared__ __align__(16) u16 Bs[128 * 32];
    int z = blockIdx.z;
    const u16* Bt = (z == 0) ? Wqt : (z == 1) ? Wkt : Wvt;
    int m0 = blockIdx.x * 128;
    f32x4 acc[4][4]; mm_zero(acc);
    mm_core(A, Bt, 128, 128, 128, m0, 0, As, Bs, acc);
    int t = threadIdx.x, w = t >> 6, l = t & 63;
    int rbase = m0 + (w >> 1) * 64 + (l >> 4) * 4;
    int cbase = (w & 1) * 64 + (l & 15);
    if (z == 0) {
        #pragma unroll
        for (int j = 0; j < 4; ++j)
            #pragma unroll
            for (int i = 0; i < 4; ++i)
                #pragma unroll
                for (int r = 0; r < 4; ++r) {
                    int row = rbase + i * 16 + r;
                    if (row < M) Q[(size_t)row * 128 + cbase + j * 16] = acc[i][j][r];
                }
    } else {
        u16* C = (z == 1) ? Kb : Vb;
        #pragma unroll
        for (int j = 0; j < 4; ++j)
            #pragma unroll
            for (int i = 0; i < 4; ++i)
                #pragma unroll
                for (int r = 0; r < 4; ++r) {
                    int row = rbase + i * 16 + r;
                    if (row < M) C[(size_t)row * 128 + cbase + j * 16] = f2bf(acc[i][j][r]);
                }
    }
}

// ---------------------------------------------------------------------------
// BatchNorm (bf16 input)
// ---------------------------------------------------------------------------
__global__ void k_bn_stats_bf(const u16* __restrict__ H, double* __restrict__ stats, int N, int C) {
    int t = threadIdx.x;
    int rpt = 256 / C;
    int rsub = t / C;
    int col = t - rsub * C;
    double s = 0.0, q = 0.0;
    for (long r = (long)blockIdx.x * rpt + rsub; r < N; r += (long)gridDim.x * rpt) {
        float v = bf2f(H[(size_t)r * C + col]);
        s += v; q += (double)v * v;
    }
    __shared__ double sh_s[256], sh_q[256];
    sh_s[t] = s; sh_q[t] = q;
    __syncthreads();
    if (t < C) {
        for (int k = 1; k < rpt; ++k) { s += sh_s[t + k * C]; q += sh_q[t + k * C]; }
        atomicAdd(&stats[t], s);
        atomicAdd(&stats[C + t], q);
    }
}

__global__ void k_bn_fin(const double* __restrict__ stats, const float* __restrict__ g,
                         const float* __restrict__ b, float* __restrict__ scale,
                         float* __restrict__ shift, int C, double invN) {
    int t = threadIdx.x;
    if (t >= C) return;
    double mean = stats[t] * invN;
    double var = stats[C + t] * invN - mean * mean;
    float sc = (float)((double)g[t] / sqrt(var + 1e-5));
    scale[t] = sc;
    shift[t] = b[t] - (float)mean * sc;
}

// bf16 -> bf16 (in-place ok)
__global__ void k_bn_relu_bb(const u16* __restrict__ in, u16* __restrict__ out,
                             const float* __restrict__ scale, const float* __restrict__ shift,
                             int total4, int cmask4) {
    int i = blockIdx.x * blockDim.x + threadIdx.x;
    if (i >= total4) return;
    int c4 = i & cmask4;
    ushort4 v = ((const ushort4*)in)[i];
    float4 sc = ((const float4*)scale)[c4];
    float4 sh = ((const float4*)shift)[c4];
    ((ushort4*)out)[i] = make_ushort4(
        f2bf(fmaxf(bf2f(v.x) * sc.x + sh.x, 0.f)), f2bf(fmaxf(bf2f(v.y) * sc.y + sh.y, 0.f)),
        f2bf(fmaxf(bf2f(v.z) * sc.z + sh.z, 0.f)), f2bf(fmaxf(bf2f(v.w) * sc.w + sh.w, 0.f)));
}

// bf16 -> f32
__global__ void k_bn_relu_bf(const u16* __restrict__ in, float* __restrict__ out,
                             const float* __restrict__ scale, const float* __restrict__ shift,
                             int total4, int cmask4) {
    int i = blockIdx.x * blockDim.x + threadIdx.x;
    if (i >= total4) return;
    int c4 = i & cmask4;
    ushort4 v = ((const ushort4*)in)[i];
    float4 sc = ((const float4*)scale)[c4];
    float4 sh = ((const float4*)shift)[c4];
    ((float4*)out)[i] = make_float4(
        fmaxf(bf2f(v.x) * sc.x + sh.x, 0.f), fmaxf(bf2f(v.y) * sc.y + sh.y, 0.f),
        fmaxf(bf2f(v.z) * sc.z + sh.z, 0.f), fmaxf(bf2f(v.w) * sc.w + sh.w, 0.f));
}

// ---------------------------------------------------------------------------
// gating helpers
// ---------------------------------------------------------------------------
__global__ void k_ln_gate(const float* __restrict__ Hg, const float* __restrict__ g,
                          const float* __restrict__ b, const float* __restrict__ Wg2,
                          const float* __restrict__ bg2, float* __restrict__ gate, int N) {
    int wid = blockIdx.x * 4 + (threadIdx.x >> 6);
    if (wid >= N) return;
    int lane = threadIdx.x & 63;
    float2 h = *(const float2*)(Hg + (size_t)wid * HD + lane * 2);
    float s1 = h.x + h.y, s2 = h.x * h.x + h.y * h.y;
    #pragma unroll
    for (int off = 32; off > 0; off >>= 1) { s1 += __shfl_xor(s1, off); s2 += __shfl_xor(s2, off); }
    float mu = s1 * (1.f / 128.f);
    float var = s2 * (1.f / 128.f) - mu * mu;
    float is = 1.0f / sqrtf(var + 1e-5f);
    float2 gg = *(const float2*)(g + lane * 2);
    float2 bb = *(const float2*)(b + lane * 2);
    float y0 = fmaxf((h.x - mu) * is * gg.x + bb.x, 0.f);
    float y1 = fmaxf((h.y - mu) * is * gg.y + bb.y, 0.f);
    float4 w = ((const float4*)Wg2)[lane];
    float t0 = y0 * w.x + y1 * w.z;
    float t1 = y0 * w.y + y1 * w.w;
    #pragma unroll
    for (int off = 32; off > 0; off >>= 1) { t0 += __shfl_xor(t0, off); t1 += __shfl_xor(t1, off); }
    if (lane == 0) {
        t0 = (t0 + bg2[0]) * 0.5f;
        t1 = (t1 + bg2[1]) * 0.5f;
        float m = fmaxf(t0, t1);
        float e0 = __expf(t0 - m), e1 = __expf(t1 - m);
        float inv = 1.0f / (e0 + e1);
        gate[(size_t)wid * 2 + 0] = e0 * inv;
        gate[(size_t)wid * 2 + 1] = e1 * inv;
    }
}

__global__ void k_resid_ln(const float* __restrict__ R0, const float* __restrict__ low,
                           const float* __restrict__ g, const float* __restrict__ b,
                           const float* __restrict__ rs_ptr, u16* __restrict__ resid, int N) {
    int wid = blockIdx.x * 4 + (threadIdx.x >> 6);
    if (wid >= N) return;
    int lane = threadIdx.x & 63;
    float rs = rs_ptr[0];
    float2 a = *(const float2*)(R0 + (size_t)wid * HD + lane * 2);
    float2 l = *(const float2*)(low + (size_t)wid * HD + lane * 2);
    float h0 = rs * (a.x - l.x), h1 = rs * (a.y - l.y);
    float s1 = h0 + h1, s2 = h0 * h0 + h1 * h1;
    #pragma unroll
    for (int off = 32; off > 0; off >>= 1) { s1 += __shfl_xor(s1, off); s2 += __shfl_xor(s2, off); }
    float mu = s1 * (1.f / 128.f);
    float var = s2 * (1.f / 128.f) - mu * mu;
    float is = 1.0f / sqrtf(var + 1e-5f);
    float2 gg = *(const float2*)(g + lane * 2);
    float2 bb = *(const float2*)(b + lane * 2);
    float y0 = (h0 - mu) * is * gg.x + bb.x;
    float y1 = (h1 - mu) * is * gg.y + bb.y;
    *(ushort2*)(resid + (size_t)wid * HD + lane * 2) = make_ushort2(f2bf(y0), f2bf(y1));
}

// ---------------------------------------------------------------------------
// fused attention: score (Q[wid] held in regs) + exp + aggregate + combine
// per edge: 8B cv + 256B K-row + 256B V-row (vs 1036B in the split version)
// ---------------------------------------------------------------------------
__global__ void k_attn_aggr(const float* __restrict__ Q, const u16* __restrict__ Kb,
                            const u16* __restrict__ Vb, const int* __restrict__ row_ptr,
                            const int2* __restrict__ cv,
                            const float* __restrict__ gate, const float* __restrict__ low,
                            float* __restrict__ high, float* __restrict__ outp, int N) {
    int wid = blockIdx.x * 4 + (threadIdx.x >> 6);
    if (wid >= N) return;
    int lane = threadIdx.x & 63;
    float2 q = *(const float2*)(Q + (size_t)wid * HD + lane * 2);
    float n0 = 0, n1 = 0, den = 0;
    int s = row_ptr[wid], e = row_ptr[wid + 1];
    int j = s;
    for (; j + 3 < e; j += 4) {
        int c[4]; ushort2 kb[4], vb[4];
        #pragma unroll
        for (int t = 0; t < 4; ++t) c[t] = cv[j + t].x;
        #pragma unroll
        for (int t = 0; t < 4; ++t) kb[t] = *(const ushort2*)(Kb + (size_t)c[t] * HD + lane * 2);
        #pragma unroll
        for (int t = 0; t < 4; ++t) vb[t] = *(const ushort2*)(Vb + (size_t)c[t] * HD + lane * 2);
        float sc[4];
        #pragma unroll
        for (int t = 0; t < 4; ++t) sc[t] = q.x * bf2f(kb[t].x) + q.y * bf2f(kb[t].y);
        #pragma unroll
        for (int off = 32; off > 0; off >>= 1) {
            #pragma unroll
            for (int t = 0; t < 4; ++t) sc[t] += __shfl_xor(sc[t], off);
        }
        #pragma unroll
        for (int t = 0; t < 4; ++t) {
            float p = sc[t] * 0.08838834764831845f;
            float ls = p > 0.f ? p : 0.2f * p;
            float ex = __expf(ls);
            n0 += ex * bf2f(vb[t].x);
            n1 += ex * bf2f(vb[t].y);
            den += ex;
        }
    }
    for (; j < e; ++j) {
        int c0 = cv[j].x;
        ushort2 kb0 = *(const ushort2*)(Kb + (size_t)c0 * HD + lane * 2);
        ushort2 vb0 = *(const ushort2*)(Vb + (size_t)c0 * HD + lane * 2);
        float sc0 = q.x * bf2f(kb0.x) + q.y * bf2f(kb0.y);
        #pragma unroll
        for (int off = 32; off > 0; off >>= 1) sc0 += __shfl_xor(sc0, off);
        float p = sc0 * 0.08838834764831845f;
        float ls = p > 0.f ? p : 0.2f * p;
        float ex = __expf(ls);
        n0 += ex * bf2f(vb0.x); n1 += ex * bf2f(vb0.y); den += ex;
    }
    float inv = 1.0f / (den + 1e-16f);
    float h0 = n0 * inv, h1 = n1 * inv;
    *(float2*)(high + (size_t)wid * HD + lane * 2) = make_float2(h0, h1);
    float g0 = gate[(size_t)wid * 2 + 0], g1 = gate[(size_t)wid * 2 + 1];
    float2 lw = *(const float2*)(low + (size_t)wid * HD + lane * 2);
    *(float2*)(outp + (size_t)wid * HD + lane * 2) = make_float2(g0 * lw.x + g1 * h0, g0 * lw.y + g1 * h1);
}

// ---------------------------------------------------------------------------
extern "C" void kernel_launch(void* const* d_in, const int* in_sizes, int n_in,
                              void* d_out, int out_size, void* d_ws, size_t ws_size,
                              hipStream_t stream) {
    const float* x      = (const float*)d_in[0];
    const int*   erow   = (const int*)d_in[1];
    const int*   ecol   = (const int*)d_in[2];
    const float* avals  = (const float*)d_in[3];
    const float* W_gc1  = (const float*)d_in[4];
    const float* bn1_g  = (const float*)d_in[6];
    const float* bn1_b  = (const float*)d_in[7];
    const float* W_gc2  = (const float*)d_in[8];
    const float* bn2_g  = (const float*)d_in[10];
    const float* bn2_b  = (const float*)d_in[11];
    const float* Wg1    = (const float*)d_in[12];
    const float* bg1    = (const float*)d_in[13];
    const float* ln_g   = (const float*)d_in[14];
    const float* ln_b   = (const float*)d_in[15];
    const float* Wg2    = (const float*)d_in[16];
    const float* bg2    = (const float*)d_in[17];
    const float* Wxp    = (const float*)d_in[18];
    const float* bxp    = (const float*)d_in[19];
    const float* rscale = (const float*)d_in[20];
    const float* rn_g   = (const float*)d_in[21];
    const float* rn_b   = (const float*)d_in[22];
    const float* Wq     = (const float*)d_in[23];
    const float* Wk     = (const float*)d_in[24];
    const float* Wv     = (const float*)d_in[25];

    const int N = in_sizes[0] / F0;   // 100000
    const int E = in_sizes[1];        // 3200000

    char* base = (char*)d_ws;
    size_t off = 0;
    auto carve = [&](size_t bytes) -> char* {
        char* p = base + off;
        off += (bytes + 255) & ~(size_t)255;
        return p;
    };
    double* stats  = (double*)carve(4096);
    float* scaleb  = (float*)carve(1024);
    float* shiftb  = (float*)carve(1024);
    int*   partials= (int*)carve(2048);
    u16* Wgc1t = (u16*)carve(65536 * 2);
    u16* Wgc2t = (u16*)carve(32768 * 2);
    u16* Wdt   = (u16*)carve(32768 * 2);
    u16* W1t   = (u16*)carve(32768 * 2);
    u16* W2t   = (u16*)carve(32768 * 2);
    u16* Wxpt  = (u16*)carve(32768 * 2);
    u16* Wqt   = (u16*)carve(16384 * 2);
    u16* Wkt   = (u16*)carve(16384 * 2);
    u16* Wvt   = (u16*)carve(16384 * 2);
    int*   row_ptr = (int*)carve((size_t)(N + 1) * 4);
    int*   cursor  = (int*)carve((size_t)N * 4);
    float* deg     = (float*)carve((size_t)N * 4);
    int2*  cv      = (int2*)carve((size_t)E * 8);        // packed (col, val)
    u16*   x_bf    = (u16*)carve((size_t)NP * F0 * 2);
    u16*   kvb     = (u16*)carve((size_t)NP * HD * 2 * 2); // Kb | Vb (bf16)
    u16*   AX_bf   = (u16*)carve((size_t)NP * F0 * 2);
    u16*   XSTD_bf = (u16*)carve((size_t)NP * F0 * 2);
    u16*   h1_bf   = (u16*)carve((size_t)NP * F0 * 2);   // S1 bf16 -> h1 -> resid
    float* BIG3    = (float*)carve((size_t)NP * HD * 4); // S2(bf16) -> R0 (f32)
    u16*   G2_bf   = (u16*)carve((size_t)NP * HD * 2);
    float* M3      = (float*)carve((size_t)NP * HD * 4); // hg -> Q
    (void)ws_size; (void)n_in; (void)out_size;

    u16*   Kb    = kvb;
    u16*   Vb    = kvb + (size_t)N * HD;
    u16*   S1_bf = h1_bf;
    u16*   S2_bf = (u16*)BIG3;                     // dead before R0 written
    u16*   resid_bf = h1_bf;                       // h1 dead after gc2 GEMM

    float* out_o    = (float*)d_out;
    float* out_gate = out_o + (size_t)N * HD;
    float* out_low  = out_gate + (size_t)N * 2;
    float* out_high = out_low + (size_t)N * HD;

    const int eb  = (E + 255) / 256;
    const int wb  = (N + 3) / 4;
    const int NB1 = (N + 1023) / 1024;
    const int gx  = (N + 127) / 128;
    const dim3 blk(256);

    // ===== CSR (hist -> scan -> single packed scatter) =====
    hipMemsetAsync(cursor, 0, (size_t)N * 4, stream);
    k_hist<<<eb, blk, 0, stream>>>(erow, cursor, E);
    k_scan_blk<<<NB1, 1024, 0, stream>>>(cursor, row_ptr + 1, partials, N);
    k_scan_part<<<1, 128, 0, stream>>>(partials, NB1);
    k_scan_add<<<NB1, 1024, 0, stream>>>(row_ptr, partials, N);
    hipMemsetAsync(cursor, 0, (size_t)N * 4, stream);
    k_scatter_cv<<<eb, blk, 0, stream>>>(erow, ecol, avals, row_ptr, cursor, cv, E);

    // ===== casts =====
    k_cast_x<<<(N * 64 + 255) / 256, blk, 0, stream>>>(x, x_bf, N * 64);
    k_prep_w<<<dim3(256, 1, 9), blk, 0, stream>>>(W_gc1, W_gc2, Wg1, Wxp, Wq, Wk, Wv,
                                                  Wgc1t, Wgc2t, Wdt, W1t, W2t, Wxpt, Wqt, Wkt, Wvt);

    // ===== spmm over x (fused finalize: AX_bf, XSTD_bf, deg directly) =====
    k_spmm_x2<<<wb, blk, 0, stream>>>(x_bf, row_ptr, cv, AX_bf, XSTD_bf, deg, N);

    // ===== low path =====
    k_mm_bf<<<dim3(gx, 2), blk, 0, stream>>>(AX_bf, Wgc1t, S1_bf, N, 256, 256);
    hipMemsetAsync(stats, 0, 4096, stream);
    k_bn_stats_bf<<<1024, blk, 0, stream>>>(S1_bf, stats, N, 256);
    k_bn_fin<<<1, blk, 0, stream>>>(stats, bn1_g, bn1_b, scaleb, shiftb, 256, 1.0 / N);
    k_bn_relu_bb<<<(N * 64 + 255) / 256, blk, 0, stream>>>(S1_bf, h1_bf, scaleb, shiftb, N * 64, 63);
    k_mm_bf<<<dim3(gx, 1), blk, 0, stream>>>(h1_bf, Wgc2t, G2_bf, N, 256, 128);
    k_spmm128<<<wb, blk, 0, stream>>>(G2_bf, row_ptr, cv, S2_bf, N);
    hipMemsetAsync(stats, 0, 2048, stream);
    k_bn_stats_bf<<<1024, blk, 0, stream>>>(S2_bf, stats, N, 128);
    k_bn_fin<<<1, blk, 0, stream>>>(stats, bn2_g, bn2_b, scaleb, shiftb, 128, 1.0 / N);
    k_bn_relu_bf<<<(N * 32 + 255) / 256, blk, 0, stream>>>(S2_bf, out_low, scaleb, shiftb, N * 32, 31);

    // ===== gating =====
    k_mm_gate<<<dim3(gx, 1), blk, 0, stream>>>(x_bf, AX_bf, XSTD_bf, Wdt, W1t, W2t,
                                               M3, bg1, Wg1 + (size_t)768 * 128, deg, N);
    k_ln_gate<<<wb, blk, 0, stream>>>(M3, ln_g, ln_b, Wg2, bg2, out_gate, N);

    // ===== high path =====
    k_mm_f32<<<dim3(gx, 1), blk, 0, stream>>>(x_bf, Wxpt, BIG3, bxp, N, 256, 128);  // R0
    k_resid_ln<<<wb, blk, 0, stream>>>(BIG3, out_low, rn_g, rn_b, rscale, resid_bf, N);
    k_mm_qkv<<<dim3(gx, 1, 3), blk, 0, stream>>>(resid_bf, Wqt, Wkt, Wvt, M3, Kb, Vb, N);
    k_attn_aggr<<<wb, blk, 0, stream>>>(M3, Kb, Vb, row_ptr, cv, out_gate, out_low, out_high, out_o, N);
}